// Round 11
// baseline (102.610 us; speedup 1.0000x reference)
//
#include <hip/hip_runtime.h>
#include <hip/hip_bf16.h>

namespace {

constexpr int T = 4, H = 128, W = 128, C = 256, HD = 8, K = 9, F = 32;
constexpr int M = T * H * W;  // 65536

typedef __attribute__((ext_vector_type(8))) short short8v;   // 8 bf16 (4 VGPR)
typedef __attribute__((ext_vector_type(4))) float f32x4;     // MFMA acc

__device__ __forceinline__ unsigned short f2bf(float f) {
  unsigned u = __float_as_uint(f);
  unsigned r = (u + 0x7fffu + ((u >> 16) & 1u)) >> 16;
  return (unsigned short)r;
}

__device__ __forceinline__ float bf2f(unsigned short u) {
  return __uint_as_float(((unsigned)u) << 16);
}

// ---------------------------------------------------------------------------
// Templated MFMA GEMM: Cout[m][n] = sum_k A[m][k] * B[n][k]  (+ bias[n])
// ALAYOUT: 0 = fp32 row-major [M][256]; 2 = bf16 head-major [head][M][32]
// ---------------------------------------------------------------------------
template <int ALAYOUT, bool OUT_F32>
__global__ __launch_bounds__(256) void mfma_gemm(
    const void* __restrict__ Aptr, const float* __restrict__ Bw,
    void* __restrict__ Cptr, const float* __restrict__ bias) {
  __shared__ unsigned short As[128][40];
  __shared__ unsigned short Bs[128][40];
  const int m0 = blockIdx.x * 128;
  const int n0 = blockIdx.y * 128;
  const int t = threadIdx.x;
  const int lane = t & 63;
  const int wid = t >> 6;
  const int wm = wid >> 1, wn = wid & 1;
  const int fr = lane & 15;
  const int kg = lane >> 4;

  f32x4 acc[4][4];
#pragma unroll
  for (int ni = 0; ni < 4; ++ni) {
    float b = 0.f;
    if (OUT_F32) b = bias[n0 + wn * 64 + ni * 16 + fr];
#pragma unroll
    for (int mi = 0; mi < 4; ++mi) {
      acc[mi][ni][0] = b; acc[mi][ni][1] = b;
      acc[mi][ni][2] = b; acc[mi][ni][3] = b;
    }
  }

  for (int k0 = 0; k0 < C; k0 += 32) {
    __syncthreads();
    if (ALAYOUT == 2) {
      const unsigned short* Ab = (const unsigned short*)Aptr;
      const size_t hb = (size_t)(k0 >> 5) * M * 32;
#pragma unroll
      for (int i = 0; i < 2; ++i) {
        const int flat = t + i * 256;          // 0..511
        const int row = flat >> 2, kc = (flat & 3) * 8;
        *(short8v*)&As[row][kc] =
            *(const short8v*)(Ab + hb + (size_t)(m0 + row) * 32 + kc);
      }
    } else {
      const float* Af = (const float*)Aptr;
#pragma unroll
      for (int i = 0; i < 4; ++i) {
        const int flat = t + i * 256;          // 0..1023
        const int row = flat >> 3, kc = (flat & 7) * 4;
        const float4 v4 = *(const float4*)(Af + (size_t)(m0 + row) * C + k0 + kc);
        ushort4 o;
        o.x = f2bf(v4.x); o.y = f2bf(v4.y); o.z = f2bf(v4.z); o.w = f2bf(v4.w);
        *(ushort4*)&As[row][kc] = o;
      }
    }
#pragma unroll
    for (int i = 0; i < 4; ++i) {
      const int flat = t + i * 256;
      const int row = flat >> 3, kc = (flat & 7) * 4;
      const float4 v4 = *(const float4*)(Bw + (size_t)(n0 + row) * C + k0 + kc);
      ushort4 o;
      o.x = f2bf(v4.x); o.y = f2bf(v4.y); o.z = f2bf(v4.z); o.w = f2bf(v4.w);
      *(ushort4*)&Bs[row][kc] = o;
    }
    __syncthreads();
    short8v af[4], bfv[4];
#pragma unroll
    for (int mi = 0; mi < 4; ++mi)
      af[mi] = *(const short8v*)&As[wm * 64 + mi * 16 + fr][kg * 8];
#pragma unroll
    for (int ni = 0; ni < 4; ++ni)
      bfv[ni] = *(const short8v*)&Bs[wn * 64 + ni * 16 + fr][kg * 8];
#pragma unroll
    for (int mi = 0; mi < 4; ++mi)
#pragma unroll
      for (int ni = 0; ni < 4; ++ni)
        acc[mi][ni] = __builtin_amdgcn_mfma_f32_16x16x32_bf16(
            af[mi], bfv[ni], acc[mi][ni], 0, 0, 0);
  }

#pragma unroll
  for (int mi = 0; mi < 4; ++mi) {
#pragma unroll
    for (int ni = 0; ni < 4; ++ni) {
      const int gcol = n0 + wn * 64 + ni * 16 + fr;
#pragma unroll
      for (int r = 0; r < 4; ++r) {
        const int grow = m0 + wm * 64 + mi * 16 + kg * 4 + r;
        if (OUT_F32) {
          ((float*)Cptr)[(size_t)grow * C + gcol] = acc[mi][ni][r];
        } else {
          ((unsigned short*)Cptr)[(size_t)grow * C + gcol] = f2bf(acc[mi][ni][r]);
        }
      }
    }
  }
}

// ---------------------------------------------------------------------------
// Gather v10: occupancy-first redesign.
// Block = (4x4 spatial tile, all 4 t, one head): halo 4x10x10 slivers x 64B
// = 25.6KB -> 6 blocks/CU; launch_bounds(256,6) (cap 85 VGPR, est ~70)
// -> 24 waves/CU ceiling (was 12).
// 256 thr = 64 outputs x 4 f-quarters (8 f each): 9 LDS reads + 72 FMA per
// thread (short chains, many waves). Metadata loaded ONCE per output, split
// across the 4 lanes of its group (fq0..2: 9 flow ints; fq3: 9 attn) and
// redistributed via 18 __shfl — no duplicate metadata fetch.
// 8192 blocks, XCD-chunked, head-fastest (all heads of a tile hit the same
// 512B v lines in the same XCD L2).
// ---------------------------------------------------------------------------
struct __attribute__((packed, aligned(4))) I4p { int a, b, c, d; };
struct __attribute__((packed, aligned(4))) F4p { float a, b, c, d; };

__global__ __launch_bounds__(256, 6) void gather_lds_kernel(
    const unsigned short* __restrict__ v, const float* __restrict__ attn,
    const int* __restrict__ flows, unsigned short* __restrict__ agg2) {
  __shared__ __align__(16) unsigned short halo[400 * 32];  // 25600 B
  // bijective XCD-chunk swizzle: 8192 = 8 XCDs x 1024. Within chunk:
  // head fastest, then tile-col, then tile-row (4 rows per XCD).
  const int nb = (blockIdx.x & 7) * 1024 + (blockIdx.x >> 3);
  const int head = nb & 7;
  const int tcol = (nb >> 3) & 31;
  const int trow = nb >> 8;          // 0..31
  const int h0 = trow * 4;
  const int w0 = tcol * 4;
  const int tid = threadIdx.x;
  const int o = tid >> 2;            // output 0..63
  const int fq = tid & 3;            // f-quarter (8 bf16 = 16B)
  const int t = o >> 4;              // t-plane (== wave id)
  const int s = o & 15;
  const int h = h0 + (s >> 2);
  const int w = w0 + (s & 3);
  const int m = (t << 14) | (h << 7) | w;

  // ---- metadata: split-loaded across the 4 lanes of this output's group ----
  const int base = ((head << 16) | m) * K;
  const int fb = base * 3;
  int ld[9];
  float law[9];
#pragma unroll
  for (int i = 0; i < 9; ++i) { ld[i] = 0; law[i] = 0.f; }
  if (fq < 3) {  // lane fq owns neighbors k = 3*fq .. 3*fq+2 (9 ints)
    const I4p g0 = *(const I4p*)(flows + fb + 9 * fq);
    const I4p g1 = *(const I4p*)(flows + fb + 9 * fq + 4);
    const int g2 = flows[fb + 9 * fq + 8];
    ld[0] = g0.a; ld[1] = g0.b; ld[2] = g0.c; ld[3] = g0.d;
    ld[4] = g1.a; ld[5] = g1.b; ld[6] = g1.c; ld[7] = g1.d; ld[8] = g2;
  } else {       // lane 3 owns the 9 attn weights
    const F4p a0 = *(const F4p*)(attn + base + 0);
    const F4p a1 = *(const F4p*)(attn + base + 4);
    const float a2 = attn[base + 8];
    law[0] = a0.a; law[1] = a0.b; law[2] = a0.c; law[3] = a0.d;
    law[4] = a1.a; law[5] = a1.b; law[6] = a1.c; law[7] = a1.d; law[8] = a2;
  }

  // ---- stage halo: 1600 x 16B pieces (6/thread + 64-thread tail) ----
  const unsigned short* vhead = v + head * F;
  auto piece_src = [&](int pi, int& ldsoff) -> const short8v* {
    const int sliver = pi >> 2, j = pi & 3;
    const int tt = sliver / 100;
    const int rem = sliver - tt * 100;
    const int hh = rem / 10;
    const int ww = rem - hh * 10;
    const int hc = min(max(h0 - 3 + hh, 0), H - 1);
    const int wc = min(max(w0 - 3 + ww, 0), W - 1);
    const int sm = (tt << 14) | (hc << 7) | wc;
    ldsoff = sliver * 32 + (j ^ (sliver & 3)) * 8;  // swizzled LDS dest
    return (const short8v*)(vhead + (size_t)sm * C + j * 8);  // linear src
  };
  {
    short8v pc[6]; int lo[6];
#pragma unroll
    for (int it = 0; it < 6; ++it) pc[it] = *piece_src(tid + it * 256, lo[it]);
    short8v pt; int lot = 0;
    if (tid < 64) pt = *piece_src(1536 + tid, lot);
#pragma unroll
    for (int it = 0; it < 6; ++it) *(short8v*)&halo[lo[it]] = pc[it];
    if (tid < 64) *(short8v*)&halo[lot] = pt;
  }

  // ---- decode own rows (fq 0..2: 3 each) ----
  int lrow[3];
#pragma unroll
  for (int i = 0; i < 3; ++i) lrow[i] = 0;
  if (fq < 3) {
#pragma unroll
    for (int i = 0; i < 3; ++i) {
      const int ts = min(max(t + ld[3 * i + 0], 0), T - 1);
      const int hs = min(max(h + ld[3 * i + 1], 0), H - 1) - (h0 - 3);
      const int ws = min(max(w + ld[3 * i + 2], 0), W - 1) - (w0 - 3);
      lrow[i] = (ts * 10 + hs) * 10 + ws;
    }
  }

  // ---- redistribute rows/weights within each 4-lane group ----
  const int baselane = (tid & 63) & ~3;
  int row[9]; float aw[9];
#pragma unroll
  for (int k = 0; k < 9; ++k) row[k] = __shfl(lrow[k % 3], baselane + k / 3, 64);
#pragma unroll
  for (int k = 0; k < 9; ++k) aw[k] = __shfl(law[k], baselane + 3, 64);

  __syncthreads();

  // ---- weighted sum from LDS (this lane's 8-elem f-quarter) ----
  float acc[8];
#pragma unroll
  for (int i = 0; i < 8; ++i) acc[i] = 0.f;
#pragma unroll
  for (int k = 0; k < 9; ++k) {
    const int rbase = row[k] * 32;
    const int jj = (fq ^ row[k]) & 3;
    const short8v p = *(const short8v*)&halo[rbase + jj * 8];
#pragma unroll
    for (int e = 0; e < 8; ++e)
      acc[e] += aw[k] * bf2f((unsigned short)p[e]);
  }

  // ---- store head-major: agg2[head][M][32], 16B per lane, 64B per group ----
  unsigned short* dst = agg2 + ((size_t)head * M + m) * F + fq * 8;
  short8v o8;
#pragma unroll
  for (int e = 0; e < 8; ++e) o8[e] = (short)f2bf(acc[e]);
  *(short8v*)dst = o8;
}

// ---------------------------------------------------------------------------
// Fallback (ws too small): fused gather + fp32 proj GEMM. Proven.
// ---------------------------------------------------------------------------
__global__ __launch_bounds__(256) void agg_proj_kernel(
    const unsigned short* __restrict__ v, const float* __restrict__ attn,
    const int* __restrict__ flows, const float* __restrict__ proj_w,
    const float* __restrict__ proj_b, float* __restrict__ out) {
  __shared__ float Agg[32][C];
  __shared__ float Bs[32][C];
  const int bid = blockIdx.x;
  const int t = bid >> 9;
  const int h0 = ((bid >> 5) & 15) * 8;
  const int w0 = (bid & 31) * 4;
  const int tid = threadIdx.x;

  const int g = tid >> 3;
  const int f4 = (tid & 7) * 4;
#pragma unroll
  for (int r = 0; r < 8; ++r) {
    const int pi = r * 32 + g;
    const int pos = pi >> 3;
    const int head = pi & 7;
    const int h = h0 + (pos >> 2);
    const int w = w0 + (pos & 3);
    const int base = (((head * T + t) * H + h) * W + w) * K;
    const int fbase = base * 3;
    float4 acc = {0.f, 0.f, 0.f, 0.f};
#pragma unroll
    for (int k = 0; k < K; ++k) {
      const int dt = flows[fbase + k * 3 + 0];
      const int dh = flows[fbase + k * 3 + 1];
      const int dw = flows[fbase + k * 3 + 2];
      const float aw = attn[base + k];
      const int tt = min(max(t + dt, 0), T - 1);
      const int hh = min(max(h + dh, 0), H - 1);
      const int ww = min(max(w + dw, 0), W - 1);
      const int mm = (tt * H + hh) * W + ww;
      const ushort4 r4 = *(const ushort4*)(v + (size_t)mm * C + head * F + f4);
      acc.x += aw * bf2f(r4.x);
      acc.y += aw * bf2f(r4.y);
      acc.z += aw * bf2f(r4.z);
      acc.w += aw * bf2f(r4.w);
    }
    *(float4*)&Agg[pos][head * F + f4] = acc;
  }
  __syncthreads();

  const int tx = tid & 31;
  const int ty = tid >> 5;
  float acc2[4][8];
  {
    const float4 b0 = *(const float4*)(proj_b + tx * 8);
    const float4 b1 = *(const float4*)(proj_b + tx * 8 + 4);
#pragma unroll
    for (int i = 0; i < 4; ++i) {
      acc2[i][0] = b0.x; acc2[i][1] = b0.y; acc2[i][2] = b0.z; acc2[i][3] = b0.w;
      acc2[i][4] = b1.x; acc2[i][5] = b1.y; acc2[i][6] = b1.z; acc2[i][7] = b1.w;
    }
  }
  for (int k0 = 0; k0 < C; k0 += 32) {
#pragma unroll
    for (int i = 0; i < 8; ++i) {
      const float4 w4 = *(const float4*)(proj_w + (size_t)tid * C + k0 + i * 4);
      Bs[i * 4 + 0][tid] = w4.x;
      Bs[i * 4 + 1][tid] = w4.y;
      Bs[i * 4 + 2][tid] = w4.z;
      Bs[i * 4 + 3][tid] = w4.w;
    }
    __syncthreads();
#pragma unroll 4
    for (int kk = 0; kk < 32; ++kk) {
      const float4 bb0 = *(const float4*)&Bs[kk][tx * 8];
      const float4 bb1 = *(const float4*)&Bs[kk][tx * 8 + 4];
      float a[4];
#pragma unroll
      for (int i = 0; i < 4; ++i) a[i] = Agg[ty * 4 + i][k0 + kk];
#pragma unroll
      for (int i = 0; i < 4; ++i) {
        acc2[i][0] += a[i] * bb0.x;
        acc2[i][1] += a[i] * bb0.y;
        acc2[i][2] += a[i] * bb0.z;
        acc2[i][3] += a[i] * bb0.w;
        acc2[i][4] += a[i] * bb1.x;
        acc2[i][5] += a[i] * bb1.y;
        acc2[i][6] += a[i] * bb1.z;
        acc2[i][7] += a[i] * bb1.w;
      }
    }
    __syncthreads();
  }
#pragma unroll
  for (int i = 0; i < 4; ++i) {
    const int pos = ty * 4 + i;
    const int h = h0 + (pos >> 2);
    const int w = w0 + (pos & 3);
    const int m = (t * H + h) * W + w;
    float4 o0, o1;
    o0.x = acc2[i][0]; o0.y = acc2[i][1]; o0.z = acc2[i][2]; o0.w = acc2[i][3];
    o1.x = acc2[i][4]; o1.y = acc2[i][5]; o1.z = acc2[i][6]; o1.w = acc2[i][7];
    *(float4*)(out + (size_t)m * C + tx * 8) = o0;
    *(float4*)(out + (size_t)m * C + tx * 8 + 4) = o1;
  }
}

}  // namespace

extern "C" void kernel_launch(void* const* d_in, const int* in_sizes, int n_in,
                              void* d_out, int out_size, void* d_ws,
                              size_t ws_size, hipStream_t stream) {
  const float* x = (const float*)d_in[0];
  const float* attn = (const float*)d_in[1];
  const int* flows = (const int*)d_in[2];
  const float* v_w = (const float*)d_in[3];
  const float* proj_w = (const float*)d_in[4];
  const float* proj_b = (const float*)d_in[5];
  float* out = (float*)d_out;

  const size_t VBYTES = (size_t)M * C * 2;  // 32 MB bf16
  unsigned short* v = (unsigned short*)d_ws;

  dim3 g1(M / 128, C / 128);
  mfma_gemm<0, false><<<g1, 256, 0, stream>>>(x, v_w, v, nullptr);

  if (ws_size >= 2 * VBYTES) {
    unsigned short* agg2 = (unsigned short*)((char*)d_ws + VBYTES);
    gather_lds_kernel<<<8192, 256, 0, stream>>>(v, attn, flows, agg2);
    mfma_gemm<2, true><<<g1, 256, 0, stream>>>(agg2, proj_w, out, proj_b);
  } else {
    const int nblk = T * (H / 8) * (W / 4);  // 2048
    agg_proj_kernel<<<nblk, 256, 0, stream>>>(v, attn, flows, proj_w, proj_b,
                                              out);
  }
}

// Round 12
// 96.922 us; speedup vs baseline: 1.0587x; 1.0587x over previous
//
#include <hip/hip_runtime.h>
#include <hip/hip_bf16.h>

namespace {

constexpr int T = 4, H = 128, W = 128, C = 256, HD = 8, K = 9, F = 32;
constexpr int M = T * H * W;  // 65536

typedef __attribute__((ext_vector_type(8))) short short8v;   // 8 bf16 (4 VGPR)
typedef __attribute__((ext_vector_type(4))) float f32x4;     // MFMA acc

__device__ __forceinline__ unsigned short f2bf(float f) {
  unsigned u = __float_as_uint(f);
  unsigned r = (u + 0x7fffu + ((u >> 16) & 1u)) >> 16;
  return (unsigned short)r;
}

__device__ __forceinline__ float bf2f(unsigned short u) {
  return __uint_as_float(((unsigned)u) << 16);
}

// ---------------------------------------------------------------------------
// Templated MFMA GEMM: Cout[m][n] = sum_k A[m][k] * B[n][k]  (+ bias[n])
// ALAYOUT: 0 = fp32 row-major [M][256]; 2 = bf16 head-major [head][M][32]
// ---------------------------------------------------------------------------
template <int ALAYOUT, bool OUT_F32>
__global__ __launch_bounds__(256) void mfma_gemm(
    const void* __restrict__ Aptr, const float* __restrict__ Bw,
    void* __restrict__ Cptr, const float* __restrict__ bias) {
  __shared__ unsigned short As[128][40];
  __shared__ unsigned short Bs[128][40];
  const int m0 = blockIdx.x * 128;
  const int n0 = blockIdx.y * 128;
  const int t = threadIdx.x;
  const int lane = t & 63;
  const int wid = t >> 6;
  const int wm = wid >> 1, wn = wid & 1;
  const int fr = lane & 15;
  const int kg = lane >> 4;

  f32x4 acc[4][4];
#pragma unroll
  for (int ni = 0; ni < 4; ++ni) {
    float b = 0.f;
    if (OUT_F32) b = bias[n0 + wn * 64 + ni * 16 + fr];
#pragma unroll
    for (int mi = 0; mi < 4; ++mi) {
      acc[mi][ni][0] = b; acc[mi][ni][1] = b;
      acc[mi][ni][2] = b; acc[mi][ni][3] = b;
    }
  }

  for (int k0 = 0; k0 < C; k0 += 32) {
    __syncthreads();
    if (ALAYOUT == 2) {
      const unsigned short* Ab = (const unsigned short*)Aptr;
      const size_t hb = (size_t)(k0 >> 5) * M * 32;
#pragma unroll
      for (int i = 0; i < 2; ++i) {
        const int flat = t + i * 256;          // 0..511
        const int row = flat >> 2, kc = (flat & 3) * 8;
        *(short8v*)&As[row][kc] =
            *(const short8v*)(Ab + hb + (size_t)(m0 + row) * 32 + kc);
      }
    } else {
      const float* Af = (const float*)Aptr;
#pragma unroll
      for (int i = 0; i < 4; ++i) {
        const int flat = t + i * 256;          // 0..1023
        const int row = flat >> 3, kc = (flat & 7) * 4;
        const float4 v4 = *(const float4*)(Af + (size_t)(m0 + row) * C + k0 + kc);
        ushort4 o;
        o.x = f2bf(v4.x); o.y = f2bf(v4.y); o.z = f2bf(v4.z); o.w = f2bf(v4.w);
        *(ushort4*)&As[row][kc] = o;
      }
    }
#pragma unroll
    for (int i = 0; i < 4; ++i) {
      const int flat = t + i * 256;
      const int row = flat >> 3, kc = (flat & 7) * 4;
      const float4 v4 = *(const float4*)(Bw + (size_t)(n0 + row) * C + k0 + kc);
      ushort4 o;
      o.x = f2bf(v4.x); o.y = f2bf(v4.y); o.z = f2bf(v4.z); o.w = f2bf(v4.w);
      *(ushort4*)&Bs[row][kc] = o;
    }
    __syncthreads();
    short8v af[4], bfv[4];
#pragma unroll
    for (int mi = 0; mi < 4; ++mi)
      af[mi] = *(const short8v*)&As[wm * 64 + mi * 16 + fr][kg * 8];
#pragma unroll
    for (int ni = 0; ni < 4; ++ni)
      bfv[ni] = *(const short8v*)&Bs[wn * 64 + ni * 16 + fr][kg * 8];
#pragma unroll
    for (int mi = 0; mi < 4; ++mi)
#pragma unroll
      for (int ni = 0; ni < 4; ++ni)
        acc[mi][ni] = __builtin_amdgcn_mfma_f32_16x16x32_bf16(
            af[mi], bfv[ni], acc[mi][ni], 0, 0, 0);
  }

#pragma unroll
  for (int mi = 0; mi < 4; ++mi) {
#pragma unroll
    for (int ni = 0; ni < 4; ++ni) {
      const int gcol = n0 + wn * 64 + ni * 16 + fr;
#pragma unroll
      for (int r = 0; r < 4; ++r) {
        const int grow = m0 + wm * 64 + mi * 16 + kg * 4 + r;
        if (OUT_F32) {
          ((float*)Cptr)[(size_t)grow * C + gcol] = acc[mi][ni][r];
        } else {
          ((unsigned short*)Cptr)[(size_t)grow * C + gcol] = f2bf(acc[mi][ni][r]);
        }
      }
    }
  }
}

// ---------------------------------------------------------------------------
// Gather v11 = r10 shape (256 thr, (256,4), 8x8 tile, 50KB halo — proven
// 50.7us with clean FETCH 65/WRITE 33) with ONE change: the piece swizzle is
// now a ROTATION jj = (j + (sliver>>1)) & 3 instead of XOR (sliver&3).
// Bank math: a 64B row covers bank-quad q = 4*(row&1) + jj. With the XOR,
// q took only 4 of 8 values over random rows (row&3 drove parity AND jj) ->
// 16 accesses/bank = 2x the 8/bank floor for a 1KB wave-read (the measured
// 5.8M conflict cycles). The rotation makes q a bijection of row&7 ->
// uniform over all 8 quads -> conflict-free floor. Same instruction count.
// ---------------------------------------------------------------------------
struct __attribute__((packed, aligned(4))) I4p { int a, b, c, d; };
struct __attribute__((packed, aligned(4))) I2p { int a, b; };
struct __attribute__((packed, aligned(4))) F4p { float a, b, c, d; };

__global__ __launch_bounds__(256, 4) void gather_lds_kernel(
    const unsigned short* __restrict__ v, const float* __restrict__ attn,
    const int* __restrict__ flows, unsigned short* __restrict__ agg2) {
  __shared__ __align__(16) unsigned short halo[4 * 14 * 14 * 32];  // 50176 B
  // bijective XCD-chunk swizzle: 2048 blocks = 8 XCDs x 256; head fastest.
  const int nb = (blockIdx.x & 7) * 256 + (blockIdx.x >> 3);
  const int head = nb & 7;
  const int tile = nb >> 3;          // 0..255 over 16x16 grid of 8x8 tiles
  const int h0 = (tile >> 4) * 8;
  const int w0 = (tile & 15) * 8;
  const int tid = threadIdx.x;
  const int s = tid & 63;            // spatial 0..63
  const int tq = tid >> 6;           // output t-plane 0..3
  const int h = h0 + (s >> 3);
  const int w = w0 + (s & 7);
  const int m = (tq << 14) | (h << 7) | w;

  // ---- metadata loads issued first (latency hides under staging) ----
  const int base = ((head << 16) | m) * K;
  const int fb = base * 3;
  const I4p f0 = *(const I4p*)(flows + fb + 0);
  const I4p f1 = *(const I4p*)(flows + fb + 4);
  const I4p f2 = *(const I4p*)(flows + fb + 8);
  const I4p f3 = *(const I4p*)(flows + fb + 12);
  const I4p f4 = *(const I4p*)(flows + fb + 16);
  const I4p f5 = *(const I4p*)(flows + fb + 20);
  const I2p f6 = *(const I2p*)(flows + fb + 24);
  const int f7 = flows[fb + 26];
  const F4p a0 = *(const F4p*)(attn + base + 0);
  const F4p a1 = *(const F4p*)(attn + base + 4);
  const float a2 = attn[base + 8];

  // ---- stage halo: 3136 x 16B pieces, batched in 2 epochs ----
  const unsigned short* vhead = v + head * F;
  auto piece_src = [&](int pi, int& ldsoff) -> const short8v* {
    const int sliver = pi >> 2, j = pi & 3;
    const int tt = sliver / 196;
    const int rem = sliver - tt * 196;
    const int hh = rem / 14;
    const int ww = rem - hh * 14;
    const int hc = min(max(h0 - 3 + hh, 0), H - 1);
    const int wc = min(max(w0 - 3 + ww, 0), W - 1);
    const int sm = (tt << 14) | (hc << 7) | wc;
    const int jj = (j + (sliver >> 1)) & 3;  // rotation swizzle (bank-uniform)
    ldsoff = sliver * 32 + jj * 8;
    return (const short8v*)(vhead + (size_t)sm * C + j * 8);  // linear src
  };
  {  // epoch A: pieces 0..1791 (7 per thread, one batched wait)
    short8v pc[7]; int lo[7];
#pragma unroll
    for (int it = 0; it < 7; ++it) pc[it] = *piece_src(tid + it * 256, lo[it]);
#pragma unroll
    for (int it = 0; it < 7; ++it) *(short8v*)&halo[lo[it]] = pc[it];
  }
  {  // epoch B: pieces 1792..3071 (5 per thread) + tail 3072..3135
    short8v pc[5]; int lo[5];
#pragma unroll
    for (int it = 0; it < 5; ++it)
      pc[it] = *piece_src(1792 + tid + it * 256, lo[it]);
    short8v pt; int lot = 0;
    if (tid < 64) pt = *piece_src(3072 + tid, lot);
#pragma unroll
    for (int it = 0; it < 5; ++it) *(short8v*)&halo[lo[it]] = pc[it];
    if (tid < 64) *(short8v*)&halo[lot] = pt;
  }
  __syncthreads();

  // ---- decode offsets -> halo rows ----
  const int d[27] = {f0.a, f0.b, f0.c, f0.d, f1.a, f1.b, f1.c, f1.d,
                     f2.a, f2.b, f2.c, f2.d, f3.a, f3.b, f3.c, f3.d,
                     f4.a, f4.b, f4.c, f4.d, f5.a, f5.b, f5.c, f5.d,
                     f6.a, f6.b, f7};
  const float aw[9] = {a0.a, a0.b, a0.c, a0.d, a1.a, a1.b, a1.c, a1.d, a2};
  int row[9];
#pragma unroll
  for (int k = 0; k < 9; ++k) {
    const int ts = min(max(tq + d[3 * k + 0], 0), T - 1);
    const int hs = min(max(h + d[3 * k + 1], 0), H - 1) - (h0 - 3);
    const int ws = min(max(w + d[3 * k + 2], 0), W - 1) - (w0 - 3);
    row[k] = (ts * 14 + hs) * 14 + ws;
  }

  // ---- weighted sum from LDS ----
  float acc[32];
#pragma unroll
  for (int i = 0; i < 32; ++i) acc[i] = 0.f;
#pragma unroll
  for (int k = 0; k < 9; ++k) {
    const int rbase = row[k] * 32;
    const int rot = (row[k] >> 1) & 3;
#pragma unroll
    for (int j = 0; j < 4; ++j) {
      const short8v p = *(const short8v*)&halo[rbase + (((j + rot) & 3)) * 8];
#pragma unroll
      for (int e = 0; e < 8; ++e)
        acc[j * 8 + e] += aw[k] * bf2f((unsigned short)p[e]);
    }
  }

  // ---- store head-major: agg2[head][M][F], 64B contiguous per thread ----
  unsigned short* dst = agg2 + ((size_t)head * M + m) * F;
#pragma unroll
  for (int j = 0; j < 4; ++j) {
    short8v o;
#pragma unroll
    for (int e = 0; e < 8; ++e) o[e] = (short)f2bf(acc[j * 8 + e]);
    *(short8v*)(dst + j * 8) = o;
  }
}

// ---------------------------------------------------------------------------
// Fallback (ws too small): fused gather + fp32 proj GEMM. Proven.
// ---------------------------------------------------------------------------
__global__ __launch_bounds__(256) void agg_proj_kernel(
    const unsigned short* __restrict__ v, const float* __restrict__ attn,
    const int* __restrict__ flows, const float* __restrict__ proj_w,
    const float* __restrict__ proj_b, float* __restrict__ out) {
  __shared__ float Agg[32][C];
  __shared__ float Bs[32][C];
  const int bid = blockIdx.x;
  const int t = bid >> 9;
  const int h0 = ((bid >> 5) & 15) * 8;
  const int w0 = (bid & 31) * 4;
  const int tid = threadIdx.x;

  const int g = tid >> 3;
  const int f4 = (tid & 7) * 4;
#pragma unroll
  for (int r = 0; r < 8; ++r) {
    const int pi = r * 32 + g;
    const int pos = pi >> 3;
    const int head = pi & 7;
    const int h = h0 + (pos >> 2);
    const int w = w0 + (pos & 3);
    const int base = (((head * T + t) * H + h) * W + w) * K;
    const int fbase = base * 3;
    float4 acc = {0.f, 0.f, 0.f, 0.f};
#pragma unroll
    for (int k = 0; k < K; ++k) {
      const int dt = flows[fbase + k * 3 + 0];
      const int dh = flows[fbase + k * 3 + 1];
      const int dw = flows[fbase + k * 3 + 2];
      const float aw = attn[base + k];
      const int tt = min(max(t + dt, 0), T - 1);
      const int hh = min(max(h + dh, 0), H - 1);
      const int ww = min(max(w + dw, 0), W - 1);
      const int mm = (tt * H + hh) * W + ww;
      const ushort4 r4 = *(const ushort4*)(v + (size_t)mm * C + head * F + f4);
      acc.x += aw * bf2f(r4.x);
      acc.y += aw * bf2f(r4.y);
      acc.z += aw * bf2f(r4.z);
      acc.w += aw * bf2f(r4.w);
    }
    *(float4*)&Agg[pos][head * F + f4] = acc;
  }
  __syncthreads();

  const int tx = tid & 31;
  const int ty = tid >> 5;
  float acc2[4][8];
  {
    const float4 b0 = *(const float4*)(proj_b + tx * 8);
    const float4 b1 = *(const float4*)(proj_b + tx * 8 + 4);
#pragma unroll
    for (int i = 0; i < 4; ++i) {
      acc2[i][0] = b0.x; acc2[i][1] = b0.y; acc2[i][2] = b0.z; acc2[i][3] = b0.w;
      acc2[i][4] = b1.x; acc2[i][5] = b1.y; acc2[i][6] = b1.z; acc2[i][7] = b1.w;
    }
  }
  for (int k0 = 0; k0 < C; k0 += 32) {
#pragma unroll
    for (int i = 0; i < 8; ++i) {
      const float4 w4 = *(const float4*)(proj_w + (size_t)tid * C + k0 + i * 4);
      Bs[i * 4 + 0][tid] = w4.x;
      Bs[i * 4 + 1][tid] = w4.y;
      Bs[i * 4 + 2][tid] = w4.z;
      Bs[i * 4 + 3][tid] = w4.w;
    }
    __syncthreads();
#pragma unroll 4
    for (int kk = 0; kk < 32; ++kk) {
      const float4 bb0 = *(const float4*)&Bs[kk][tx * 8];
      const float4 bb1 = *(const float4*)&Bs[kk][tx * 8 + 4];
      float a[4];
#pragma unroll
      for (int i = 0; i < 4; ++i) a[i] = Agg[ty * 4 + i][k0 + kk];
#pragma unroll
      for (int i = 0; i < 4; ++i) {
        acc2[i][0] += a[i] * bb0.x;
        acc2[i][1] += a[i] * bb0.y;
        acc2[i][2] += a[i] * bb0.z;
        acc2[i][3] += a[i] * bb0.w;
        acc2[i][4] += a[i] * bb1.x;
        acc2[i][5] += a[i] * bb1.y;
        acc2[i][6] += a[i] * bb1.z;
        acc2[i][7] += a[i] * bb1.w;
      }
    }
    __syncthreads();
  }
#pragma unroll
  for (int i = 0; i < 4; ++i) {
    const int pos = ty * 4 + i;
    const int h = h0 + (pos >> 2);
    const int w = w0 + (pos & 3);
    const int m = (t * H + h) * W + w;
    float4 o0, o1;
    o0.x = acc2[i][0]; o0.y = acc2[i][1]; o0.z = acc2[i][2]; o0.w = acc2[i][3];
    o1.x = acc2[i][4]; o1.y = acc2[i][5]; o1.z = acc2[i][6]; o1.w = acc2[i][7];
    *(float4*)(out + (size_t)m * C + tx * 8) = o0;
    *(float4*)(out + (size_t)m * C + tx * 8 + 4) = o1;
  }
}

}  // namespace

extern "C" void kernel_launch(void* const* d_in, const int* in_sizes, int n_in,
                              void* d_out, int out_size, void* d_ws,
                              size_t ws_size, hipStream_t stream) {
  const float* x = (const float*)d_in[0];
  const float* attn = (const float*)d_in[1];
  const int* flows = (const int*)d_in[2];
  const float* v_w = (const float*)d_in[3];
  const float* proj_w = (const float*)d_in[4];
  const float* proj_b = (const float*)d_in[5];
  float* out = (float*)d_out;

  const size_t VBYTES = (size_t)M * C * 2;  // 32 MB bf16
  unsigned short* v = (unsigned short*)d_ws;

  dim3 g1(M / 128, C / 128);
  mfma_gemm<0, false><<<g1, 256, 0, stream>>>(x, v_w, v, nullptr);

  if (ws_size >= 2 * VBYTES) {
    unsigned short* agg2 = (unsigned short*)((char*)d_ws + VBYTES);
    gather_lds_kernel<<<2048, 256, 0, stream>>>(v, attn, flows, agg2);
    mfma_gemm<2, true><<<g1, 256, 0, stream>>>(agg2, proj_w, out, proj_b);
  } else {
    const int nblk = T * (H / 8) * (W / 4);  // 2048
    agg_proj_kernel<<<nblk, 256, 0, stream>>>(v, attn, flows, proj_w, proj_b,
                                              out);
  }
}